// Round 3
// baseline (399.324 us; speedup 1.0000x reference)
//
#include <hip/hip_runtime.h>

typedef unsigned short u16;
typedef __attribute__((ext_vector_type(8))) short bf16x8;
typedef __attribute__((ext_vector_type(4))) float f32x4;

#define SEQ 4096
#define DIM 1024

// ---------- bf16 helpers (OCP bf16 = top 16 bits of fp32, RNE) ----------
__device__ __forceinline__ u16 f2bf(float f) {
  unsigned u = __float_as_uint(f);
  return (u16)((u + 0x7fffu + ((u >> 16) & 1u)) >> 16);
}
__device__ __forceinline__ float bf2f(u16 h) {
  return __uint_as_float(((unsigned)h) << 16);
}

// ---------- async global->LDS, 16B per lane ----------
__device__ __forceinline__ void gload_lds16(const void* g, void* l) {
  __builtin_amdgcn_global_load_lds(
      (const __attribute__((address_space(1))) void*)g,
      (__attribute__((address_space(3))) void*)l, 16, 0, 0);
}

// Stage a 128x32 bf16 tile into LDS with the swizzled slot map
//   slot(row, gch) = (row>>4)*64 + gch*16 + (row&15)      (gch = k-chunk of 8)
// so that a fragment read (16 rows x one k-chunk per lane) resolves to
// addr = base + lane*16B  -> lane-linear, bank-conflict-free ds_read_b128.
// global_load_lds writes chunk c = it*256 + tid at LDS slot c (wave-uniform
// base + lane*16, m104/m108); we invert the map on the gather side:
//   row = (c>>6)*16 + (c&15),  gch = (c>>4)&3.
__device__ __forceinline__ void stage_tile(const u16* __restrict__ g, int ld,
                                           u16* lds, int tid) {
  const int w = tid >> 6;
#pragma unroll
  for (int it = 0; it < 2; ++it) {
    int c = it * 256 + tid;
    int row = ((c >> 6) << 4) | (c & 15);
    int gch = (c >> 4) & 3;
    gload_lds16(g + (size_t)row * ld + gch * 8, lds + (size_t)(it * 256 + w * 64) * 8);
  }
}

// ---------- fused multi-pair NT GEMM core ----------
// C[128,128] += A0*B0^T  (+ A0*B1^T + A1*B0^T for NPAIR==3)
// All operand tiles staged ONCE per k0; 16/48 MFMA per barrier pair.
// 4 waves in 2x2; each wave 64x64 as 4x4 of 16x16x32 MFMA.
// Fragment for (wm,mi): slot base (wm*4+mi)*64, lane-linear -> elem offset
//   wm*2048 + mi*512 + lane*8.
template <int NPAIR>
__device__ __forceinline__ void gemm_multi(
    const u16* A0, const u16* A1,
    const u16* B0, const u16* B1,
    int K, int ldA, int ldB,
    u16* lds, f32x4 (&acc)[4][4]) {
  const int tid = threadIdx.x;
  const int w = tid >> 6, l = tid & 63;
  const int wm = w >> 1, wn = w & 1;
  u16* lA0 = lds;
  u16* lB0 = lds + 4096;
  u16* lA1 = lds + 8192;
  u16* lB1 = lds + 12288;

#pragma unroll
  for (int mi = 0; mi < 4; ++mi)
#pragma unroll
    for (int ni = 0; ni < 4; ++ni)
      acc[mi][ni] = (f32x4){0.f, 0.f, 0.f, 0.f};

  const int ao = wm * 2048 + l * 8;
  const int bo = wn * 2048 + l * 8;

  for (int k0 = 0; k0 < K; k0 += 32) {
    stage_tile(A0 + k0, ldA, lA0, tid);
    stage_tile(B0 + k0, ldB, lB0, tid);
    if constexpr (NPAIR >= 3) {
      stage_tile(A1 + k0, ldA, lA1, tid);
      stage_tile(B1 + k0, ldB, lB1, tid);
    }
    __syncthreads();
    bf16x8 a0[4], b0[4];
#pragma unroll
    for (int i = 0; i < 4; ++i) {
      a0[i] = *(const bf16x8*)(lA0 + ao + i * 512);
      b0[i] = *(const bf16x8*)(lB0 + bo + i * 512);
    }
#pragma unroll
    for (int mi = 0; mi < 4; ++mi)
#pragma unroll
      for (int ni = 0; ni < 4; ++ni)
        acc[mi][ni] = __builtin_amdgcn_mfma_f32_16x16x32_bf16(
            a0[mi], b0[ni], acc[mi][ni], 0, 0, 0);
    if constexpr (NPAIR >= 3) {
      bf16x8 b1[4];
#pragma unroll
      for (int i = 0; i < 4; ++i) b1[i] = *(const bf16x8*)(lB1 + bo + i * 512);
#pragma unroll
      for (int mi = 0; mi < 4; ++mi)
#pragma unroll
        for (int ni = 0; ni < 4; ++ni)
          acc[mi][ni] = __builtin_amdgcn_mfma_f32_16x16x32_bf16(
              a0[mi], b1[ni], acc[mi][ni], 0, 0, 0);
      bf16x8 a1[4];
#pragma unroll
      for (int i = 0; i < 4; ++i) a1[i] = *(const bf16x8*)(lA1 + ao + i * 512);
#pragma unroll
      for (int mi = 0; mi < 4; ++mi)
#pragma unroll
        for (int ni = 0; ni < 4; ++ni)
          acc[mi][ni] = __builtin_amdgcn_mfma_f32_16x16x32_bf16(
              a1[mi], b0[ni], acc[mi][ni], 0, 0, 0);
    }
    __syncthreads();
  }
}

// C/D layout (m89/m91 verified): lane l, reg r -> row=(l>>4)*4+r, col=l&15
#define EPILOGUE_IDX                                          \
  const int tid = threadIdx.x, w = tid >> 6, l = tid & 63;    \
  const int wm = w >> 1, wn = w & 1, lr = l & 15, q = l >> 4; \
  (void)tid;

// ---------- kernels ----------

// z=0: X fp32 -> hi/lo bf16 split (elementwise)
// z=1..3: W [1024][1024] fp32 -> transposed bf16 [out][in]; hi/lo for Wq,Wk, hi-only Wv
__global__ __launch_bounds__(256) void prep_kernel(
    const float* __restrict__ X,
    const float* __restrict__ W0, const float* __restrict__ W1, const float* __restrict__ W2,
    u16* __restrict__ Xh, u16* __restrict__ Xl,
    u16* __restrict__ H0, u16* __restrict__ L0,
    u16* __restrict__ H1, u16* __restrict__ L1,
    u16* __restrict__ H2) {
  const int z = blockIdx.z;
  const int tx = threadIdx.x, ty = threadIdx.y;
  if (z == 0) {
    // 1024 blocks x 256 threads x 16 elems = 4M
    int idx = (blockIdx.y * 32 + blockIdx.x) * 256 + ty * 32 + tx;
    int i0 = idx * 16;
#pragma unroll
    for (int j = 0; j < 4; ++j) {
      int i = i0 + j * 4;
      float4 x = *(const float4*)(X + i);
      ushort4 h, lo;
      float v;
      v = x.x; h.x = f2bf(v); lo.x = f2bf(v - bf2f(h.x));
      v = x.y; h.y = f2bf(v); lo.y = f2bf(v - bf2f(h.y));
      v = x.z; h.z = f2bf(v); lo.z = f2bf(v - bf2f(h.z));
      v = x.w; h.w = f2bf(v); lo.w = f2bf(v - bf2f(h.w));
      *(ushort4*)(Xh + i) = h;
      *(ushort4*)(Xl + i) = lo;
    }
    return;
  }
  __shared__ float t[32][33];
  const float* W = (z == 1) ? W0 : (z == 2) ? W1 : W2;
  u16* H = (z == 1) ? H0 : (z == 2) ? H1 : H2;
  u16* L = (z == 1) ? L0 : (z == 2) ? L1 : nullptr;
  const int i0 = blockIdx.y * 32, o0 = blockIdx.x * 32;
#pragma unroll
  for (int m = 0; m < 4; ++m)
    t[ty + 8 * m][tx] = W[(size_t)(i0 + ty + 8 * m) * DIM + o0 + tx];
  __syncthreads();
#pragma unroll
  for (int m = 0; m < 4; ++m) {
    float v = t[tx][ty + 8 * m];
    u16 h = f2bf(v);
    size_t o = (size_t)(o0 + ty + 8 * m) * DIM + i0 + tx;
    H[o] = h;
    if (L) L[o] = f2bf(v - bf2f(h));
  }
}

// z=0: Q = X Wq (split-precision, split out)  z=1: K likewise
// z=2: VT = Wv^T X^T (single-pass bf16, written directly transposed [DIM][SEQ])
__global__ __launch_bounds__(256) void qkv_kernel(
    const u16* __restrict__ Xh, const u16* __restrict__ Xl,
    const u16* __restrict__ Wh0, const u16* __restrict__ Wl0,
    const u16* __restrict__ Wh1, const u16* __restrict__ Wl1,
    const u16* __restrict__ Wh2,
    u16* __restrict__ Qh, u16* __restrict__ Ql,
    u16* __restrict__ Kh, u16* __restrict__ Kl,
    u16* __restrict__ VT) {
  __shared__ __align__(16) u16 lds[4 * 4096];
  const int z = blockIdx.z;
  f32x4 acc[4][4];
  if (z < 2) {
    const u16* Wh = z ? Wh1 : Wh0;
    const u16* Wl = z ? Wl1 : Wl0;
    const int row0 = blockIdx.y * 128, col0 = blockIdx.x * 128;
    gemm_multi<3>(Xh + (size_t)row0 * DIM, Xl + (size_t)row0 * DIM,
                  Wh + (size_t)col0 * DIM, Wl + (size_t)col0 * DIM,
                  DIM, DIM, DIM, lds, acc);
    EPILOGUE_IDX
    u16* H = z ? Kh : Qh;
    u16* L = z ? Kl : Ql;
#pragma unroll
    for (int mi = 0; mi < 4; ++mi)
#pragma unroll
      for (int ni = 0; ni < 4; ++ni)
#pragma unroll
        for (int r = 0; r < 4; ++r) {
          int row = row0 + wm * 64 + mi * 16 + q * 4 + r;
          int col = col0 + wn * 64 + ni * 16 + lr;
          float v = acc[mi][ni][r];
          u16 h = f2bf(v);
          size_t o = (size_t)row * DIM + col;
          H[o] = h;
          L[o] = f2bf(v - bf2f(h));
        }
  } else {
    const int row0 = blockIdx.x * 128;  // over DIM
    const int col0 = blockIdx.y * 128;  // over SEQ
    gemm_multi<1>(Wh2 + (size_t)row0 * DIM, nullptr,
                  Xh + (size_t)col0 * DIM, nullptr,
                  DIM, DIM, DIM, lds, acc);
    EPILOGUE_IDX
#pragma unroll
    for (int mi = 0; mi < 4; ++mi)
#pragma unroll
      for (int ni = 0; ni < 4; ++ni)
#pragma unroll
        for (int r = 0; r < 4; ++r) {
          int row = row0 + wm * 64 + mi * 16 + q * 4 + r;
          int col = col0 + wn * 64 + ni * 16 + lr;
          VT[(size_t)row * SEQ + col] = f2bf(acc[mi][ni][r]);
        }
  }
}

// S = (Q K^T) * 1/32, split-precision fused 3-pair, fp32 out
__global__ __launch_bounds__(256) void s_kernel(
    const u16* __restrict__ Qh, const u16* __restrict__ Ql,
    const u16* __restrict__ Kh, const u16* __restrict__ Kl,
    float* __restrict__ S) {
  __shared__ __align__(16) u16 lds[4 * 4096];
  const int row0 = blockIdx.y * 128, col0 = blockIdx.x * 128;
  f32x4 acc[4][4];
  gemm_multi<3>(Qh + (size_t)row0 * DIM, Ql + (size_t)row0 * DIM,
                Kh + (size_t)col0 * DIM, Kl + (size_t)col0 * DIM,
                DIM, DIM, DIM, lds, acc);
  EPILOGUE_IDX
  const float scale = 0.03125f;  // 1/sqrt(1024)
#pragma unroll
  for (int mi = 0; mi < 4; ++mi)
#pragma unroll
    for (int ni = 0; ni < 4; ++ni)
#pragma unroll
      for (int r = 0; r < 4; ++r) {
        int row = row0 + wm * 64 + mi * 16 + q * 4 + r;
        int col = col0 + wn * 64 + ni * 16 + lr;
        S[(size_t)row * SEQ + col] = acc[mi][ni][r] * scale;
      }
}

// row softmax: S fp32 [4096][4096] -> P bf16
__global__ __launch_bounds__(256) void softmax_kernel(const float* __restrict__ S,
                                                      u16* __restrict__ P) {
  const int row = blockIdx.x;
  const float* s = S + (size_t)row * SEQ;
  const int tid = threadIdx.x;
  float v[16];
  float mx = -3.4e38f;
#pragma unroll
  for (int i = 0; i < 16; ++i) {
    v[i] = s[tid + i * 256];
    mx = fmaxf(mx, v[i]);
  }
#pragma unroll
  for (int off = 32; off; off >>= 1) mx = fmaxf(mx, __shfl_xor(mx, off));
  __shared__ float red[8];
  const int w = tid >> 6, l = tid & 63;
  if (l == 0) red[w] = mx;
  __syncthreads();
  mx = fmaxf(fmaxf(red[0], red[1]), fmaxf(red[2], red[3]));
  float sum = 0.f;
#pragma unroll
  for (int i = 0; i < 16; ++i) {
    v[i] = __expf(v[i] - mx);
    sum += v[i];
  }
#pragma unroll
  for (int off = 32; off; off >>= 1) sum += __shfl_xor(sum, off);
  if (l == 0) red[4 + w] = sum;
  __syncthreads();
  sum = red[4] + red[5] + red[6] + red[7];
  const float inv = 1.f / sum;
  u16* p = P + (size_t)row * SEQ;
#pragma unroll
  for (int i = 0; i < 16; ++i) p[tid + i * 256] = f2bf(v[i] * inv);
}

// O partial = P[:, z*1024:(z+1)*1024] @ V[z*1024:(z+1)*1024, :]  (split-K=4)
__global__ __launch_bounds__(256) void o_kernel(const u16* __restrict__ P,
                                                const u16* __restrict__ VT,
                                                float* __restrict__ Opart) {
  __shared__ __align__(16) u16 lds[2 * 4096];
  const int z = blockIdx.z;
  const int row0 = blockIdx.y * 128, col0 = blockIdx.x * 128;
  const u16* A = P + (size_t)row0 * SEQ + z * 1024;
  const u16* B = VT + (size_t)col0 * SEQ + z * 1024;
  f32x4 acc[4][4];
  gemm_multi<1>(A, nullptr, B, nullptr, 1024, SEQ, SEQ, lds, acc);
  EPILOGUE_IDX
  float* O = Opart + (size_t)z * SEQ * DIM;
#pragma unroll
  for (int mi = 0; mi < 4; ++mi)
#pragma unroll
    for (int ni = 0; ni < 4; ++ni)
#pragma unroll
      for (int r = 0; r < 4; ++r) {
        int row = row0 + wm * 64 + mi * 16 + q * 4 + r;
        int col = col0 + wn * 64 + ni * 16 + lr;
        O[(size_t)row * DIM + col] = acc[mi][ni][r];
      }
}

__global__ __launch_bounds__(256) void o_reduce_kernel(const float* __restrict__ Op,
                                                       float* __restrict__ O) {
  const size_t N = (size_t)SEQ * DIM;
  size_t i = ((size_t)blockIdx.x * 256 + threadIdx.x) * 4;
  float4 a = *(const float4*)(Op + i);
  float4 b = *(const float4*)(Op + N + i);
  float4 c = *(const float4*)(Op + 2 * N + i);
  float4 d = *(const float4*)(Op + 3 * N + i);
  float4 r;
  r.x = (a.x + b.x) + (c.x + d.x);
  r.y = (a.y + b.y) + (c.y + d.y);
  r.z = (a.z + b.z) + (c.z + d.z);
  r.w = (a.w + b.w) + (c.w + d.w);
  *(float4*)(O + i) = r;
}

// ---------- launch ----------
extern "C" void kernel_launch(void* const* d_in, const int* in_sizes, int n_in,
                              void* d_out, int out_size, void* d_ws, size_t ws_size,
                              hipStream_t stream) {
  const float* X = (const float*)d_in[0];
  const float* Wq = (const float*)d_in[1];
  const float* Wk = (const float*)d_in[2];
  const float* Wv = (const float*)d_in[3];

  const size_t MB = 1024 * 1024;
  char* w = (char*)d_ws;
  u16* Xh = (u16*)(w + 0 * MB);    // 8 MB
  u16* Xl = (u16*)(w + 8 * MB);    // 8 MB
  u16* WqhT = (u16*)(w + 16 * MB); // 2 MB each
  u16* WqlT = (u16*)(w + 18 * MB);
  u16* WkhT = (u16*)(w + 20 * MB);
  u16* WklT = (u16*)(w + 22 * MB);
  u16* WvhT = (u16*)(w + 24 * MB);
  u16* Qh = (u16*)(w + 26 * MB);   // 8 MB each
  u16* Ql = (u16*)(w + 34 * MB);
  u16* Kh = (u16*)(w + 42 * MB);
  u16* Kl = (u16*)(w + 50 * MB);
  u16* VT = (u16*)(w + 58 * MB);   // 8 MB
  float* S = (float*)(w + 66 * MB);    // 64 MB
  u16* P = (u16*)(w + 26 * MB);        // aliases Qh..Kl (dead after s_kernel)
  float* Opart = (float*)(w + 66 * MB);// aliases S (dead after softmax), 64 MB
  // total: 130 MB

  prep_kernel<<<dim3(32, 32, 4), dim3(32, 8), 0, stream>>>(
      X, Wq, Wk, Wv, Xh, Xl, WqhT, WqlT, WkhT, WklT, WvhT);
  qkv_kernel<<<dim3(DIM / 128, SEQ / 128, 3), 256, 0, stream>>>(
      Xh, Xl, WqhT, WqlT, WkhT, WklT, WvhT, Qh, Ql, Kh, Kl, VT);
  s_kernel<<<dim3(SEQ / 128, SEQ / 128), 256, 0, stream>>>(Qh, Ql, Kh, Kl, S);
  softmax_kernel<<<SEQ, 256, 0, stream>>>(S, P);
  o_kernel<<<dim3(DIM / 128, SEQ / 128, 4), 256, 0, stream>>>(P, VT, Opart);
  o_reduce_kernel<<<(SEQ * DIM) / (256 * 4), 256, 0, stream>>>(Opart, (float*)d_out);
}

// Round 4
// 340.617 us; speedup vs baseline: 1.1724x; 1.1724x over previous
//
#include <hip/hip_runtime.h>

typedef unsigned short u16;
typedef __attribute__((ext_vector_type(8))) short bf16x8;
typedef __attribute__((ext_vector_type(4))) float f32x4;

#define SEQ 4096
#define DIM 1024

// ---------- bf16 helpers (OCP bf16 = top 16 bits of fp32, RNE) ----------
__device__ __forceinline__ u16 f2bf(float f) {
  unsigned u = __float_as_uint(f);
  return (u16)((u + 0x7fffu + ((u >> 16) & 1u)) >> 16);
}
__device__ __forceinline__ float bf2f(u16 h) {
  return __uint_as_float(((unsigned)h) << 16);
}

// ---------- async global->LDS, 16B per lane ----------
__device__ __forceinline__ void gload_lds16(const void* g, void* l) {
  __builtin_amdgcn_global_load_lds(
      (const __attribute__((address_space(1))) void*)g,
      (__attribute__((address_space(3))) void*)l, 16, 0, 0);
}

// ---------- tile-packed operand layout ----------
// Matrix [R][Kd] stored as 128x32 tiles; tile (rb,kb) at (rb*(Kd/32)+kb)*4096
// elems. Within tile, 16B slot s = ((r7>>4)<<6) | ((c5>>3)<<4) | (r7&15),
// elem-in-slot = c5&7  (r7=row&127, c5=col&31).
// Property 1 (global): staging chunk c reads g+c*8 -> consecutive lanes
//   perfectly contiguous (1KB/instr) -> TA coalescer fully merges (r3 showed
//   coalescing is lane-order sensitive; this is the safest possible order).
// Property 2 (LDS): frag read for row-block wb, sub-tile mi, lane l lands at
//   elem (wb*4+mi)*512 + l*8 -> lane-linear 16B -> zero bank conflicts
//   (counter-verified in r3: SQ_LDS_BANK_CONFLICT == 0 for this pattern).
__device__ __forceinline__ size_t pkoff(int row, int col, int kd) {
  int tile = (row >> 7) * (kd >> 5) + (col >> 5);
  int r7 = row & 127, c5 = col & 31;
  int slot = ((r7 >> 4) << 6) | ((c5 >> 3) << 4) | (r7 & 15);
  return (size_t)tile * 4096 + (size_t)(slot * 8 + (c5 & 7));
}

// stage one packed 128x32 tile (4096 elems, contiguous) into LDS
__device__ __forceinline__ void stage_tile_pk(const u16* __restrict__ g,
                                              u16* lds, int tid) {
  const int w = tid >> 6;
  gload_lds16(g + (size_t)tid * 8, lds + (size_t)(w * 64) * 8);
  gload_lds16(g + (size_t)(256 + tid) * 8, lds + (size_t)(256 + w * 64) * 8);
}

// ---------- fused multi-pair NT GEMM core (packed operands, BK=32) ----------
// C[128,128] += A0*B0^T (+ A0*B1^T + A1*B0^T for NPAIR==3)
// 4 waves 2x2; wave computes 64x64 as 4x4 of 16x16x32 MFMA.
template <int NPAIR>
__device__ __forceinline__ void gemm_multi_pk(
    const u16* A0, const u16* A1, const u16* B0, const u16* B1,
    int nkb, u16* lds, f32x4 (&acc)[4][4]) {
  const int tid = threadIdx.x;
  const int w = tid >> 6, l = tid & 63;
  const int wm = w >> 1, wn = w & 1;
  u16* lA0 = lds;
  u16* lB0 = lds + 4096;
  u16* lA1 = lds + 8192;
  u16* lB1 = lds + 12288;

#pragma unroll
  for (int mi = 0; mi < 4; ++mi)
#pragma unroll
    for (int ni = 0; ni < 4; ++ni)
      acc[mi][ni] = (f32x4){0.f, 0.f, 0.f, 0.f};

  const int ao = wm * 2048 + l * 8;
  const int bo = wn * 2048 + l * 8;

  for (int kb = 0; kb < nkb; ++kb) {
    stage_tile_pk(A0 + (size_t)kb * 4096, lA0, tid);
    stage_tile_pk(B0 + (size_t)kb * 4096, lB0, tid);
    if constexpr (NPAIR >= 3) {
      stage_tile_pk(A1 + (size_t)kb * 4096, lA1, tid);
      stage_tile_pk(B1 + (size_t)kb * 4096, lB1, tid);
    }
    __syncthreads();
    bf16x8 a0[4], b0[4];
#pragma unroll
    for (int i = 0; i < 4; ++i) {
      a0[i] = *(const bf16x8*)(lA0 + ao + i * 512);
      b0[i] = *(const bf16x8*)(lB0 + bo + i * 512);
    }
#pragma unroll
    for (int mi = 0; mi < 4; ++mi)
#pragma unroll
      for (int ni = 0; ni < 4; ++ni)
        acc[mi][ni] = __builtin_amdgcn_mfma_f32_16x16x32_bf16(
            a0[mi], b0[ni], acc[mi][ni], 0, 0, 0);
    if constexpr (NPAIR >= 3) {
      bf16x8 b1[4];
#pragma unroll
      for (int i = 0; i < 4; ++i) b1[i] = *(const bf16x8*)(lB1 + bo + i * 512);
#pragma unroll
      for (int mi = 0; mi < 4; ++mi)
#pragma unroll
        for (int ni = 0; ni < 4; ++ni)
          acc[mi][ni] = __builtin_amdgcn_mfma_f32_16x16x32_bf16(
              a0[mi], b1[ni], acc[mi][ni], 0, 0, 0);
      bf16x8 a1[4];
#pragma unroll
      for (int i = 0; i < 4; ++i) a1[i] = *(const bf16x8*)(lA1 + ao + i * 512);
#pragma unroll
      for (int mi = 0; mi < 4; ++mi)
#pragma unroll
        for (int ni = 0; ni < 4; ++ni)
          acc[mi][ni] = __builtin_amdgcn_mfma_f32_16x16x32_bf16(
              a1[mi], b0[ni], acc[mi][ni], 0, 0, 0);
    }
    __syncthreads();
  }
}

// ---------- single-pair NT GEMM core, BK=64 (two packed tiles/barrier) ----------
__device__ __forceinline__ void gemm_one64(
    const u16* A, const u16* B, int nkb, u16* lds, f32x4 (&acc)[4][4]) {
  const int tid = threadIdx.x;
  const int w = tid >> 6, l = tid & 63;
  const int wm = w >> 1, wn = w & 1;
  u16* lA = lds;          // 2 tiles
  u16* lB = lds + 8192;   // 2 tiles

#pragma unroll
  for (int mi = 0; mi < 4; ++mi)
#pragma unroll
    for (int ni = 0; ni < 4; ++ni)
      acc[mi][ni] = (f32x4){0.f, 0.f, 0.f, 0.f};

  const int ao = wm * 2048 + l * 8;
  const int bo = wn * 2048 + l * 8;

  for (int kb = 0; kb < nkb; kb += 2) {
    stage_tile_pk(A + (size_t)kb * 4096, lA, tid);
    stage_tile_pk(A + (size_t)(kb + 1) * 4096, lA + 4096, tid);
    stage_tile_pk(B + (size_t)kb * 4096, lB, tid);
    stage_tile_pk(B + (size_t)(kb + 1) * 4096, lB + 4096, tid);
    __syncthreads();
#pragma unroll
    for (int h = 0; h < 2; ++h) {
      bf16x8 av[4], bv[4];
#pragma unroll
      for (int i = 0; i < 4; ++i) {
        av[i] = *(const bf16x8*)(lA + h * 4096 + ao + i * 512);
        bv[i] = *(const bf16x8*)(lB + h * 4096 + bo + i * 512);
      }
#pragma unroll
      for (int mi = 0; mi < 4; ++mi)
#pragma unroll
        for (int ni = 0; ni < 4; ++ni)
          acc[mi][ni] = __builtin_amdgcn_mfma_f32_16x16x32_bf16(
              av[mi], bv[ni], acc[mi][ni], 0, 0, 0);
    }
    __syncthreads();
  }
}

// C/D layout (m89/m91 verified): lane l, reg r -> row=(l>>4)*4+r, col=l&15
#define EPILOGUE_IDX                                          \
  const int tid = threadIdx.x, w = tid >> 6, l = tid & 63;    \
  const int wm = w >> 1, wn = w & 1, lr = l & 15, q = l >> 4; \
  (void)tid;

// ---------- kernels ----------

// z=0: X fp32 -> hi/lo bf16, tile-packed (Kd=DIM)
// z=1..3: W fp32 [in][out] -> W^T bf16 [out][in] tile-packed; hi/lo for Wq,Wk, hi for Wv
__global__ __launch_bounds__(256) void prep_kernel(
    const float* __restrict__ X,
    const float* __restrict__ W0, const float* __restrict__ W1, const float* __restrict__ W2,
    u16* __restrict__ Xh, u16* __restrict__ Xl,
    u16* __restrict__ H0, u16* __restrict__ L0,
    u16* __restrict__ H1, u16* __restrict__ L1,
    u16* __restrict__ H2) {
  const int z = blockIdx.z;
  const int tx = threadIdx.x, ty = threadIdx.y;
  if (z == 0) {
    int idx = (blockIdx.y * 32 + blockIdx.x) * 256 + ty * 32 + tx;
    int row = idx >> 6;
    int c0 = (idx & 63) * 16;
    u16 h[16], lo[16];
#pragma unroll
    for (int j = 0; j < 4; ++j) {
      float4 x = *(const float4*)(X + (size_t)row * DIM + c0 + j * 4);
      float v;
      v = x.x; h[j*4+0] = f2bf(v); lo[j*4+0] = f2bf(v - bf2f(h[j*4+0]));
      v = x.y; h[j*4+1] = f2bf(v); lo[j*4+1] = f2bf(v - bf2f(h[j*4+1]));
      v = x.z; h[j*4+2] = f2bf(v); lo[j*4+2] = f2bf(v - bf2f(h[j*4+2]));
      v = x.w; h[j*4+3] = f2bf(v); lo[j*4+3] = f2bf(v - bf2f(h[j*4+3]));
    }
    size_t o0 = pkoff(row, c0, DIM);
    size_t o1 = pkoff(row, c0 + 8, DIM);
#pragma unroll
    for (int j = 0; j < 2; ++j) {
      *(ushort4*)(Xh + o0 + j * 4) = *(ushort4*)(h + j * 4);
      *(ushort4*)(Xl + o0 + j * 4) = *(ushort4*)(lo + j * 4);
      *(ushort4*)(Xh + o1 + j * 4) = *(ushort4*)(h + 8 + j * 4);
      *(ushort4*)(Xl + o1 + j * 4) = *(ushort4*)(lo + 8 + j * 4);
    }
    return;
  }
  __shared__ float t[32][33];
  const float* W = (z == 1) ? W0 : (z == 2) ? W1 : W2;
  u16* H = (z == 1) ? H0 : (z == 2) ? H1 : H2;
  u16* L = (z == 1) ? L0 : (z == 2) ? L1 : nullptr;
  const int i0 = blockIdx.y * 32, o0 = blockIdx.x * 32;
#pragma unroll
  for (int m = 0; m < 4; ++m)
    t[ty + 8 * m][tx] = W[(size_t)(i0 + ty + 8 * m) * DIM + o0 + tx];
  __syncthreads();
#pragma unroll
  for (int m = 0; m < 4; ++m) {
    float v = t[tx][ty + 8 * m];
    u16 h = f2bf(v);
    size_t o = pkoff(o0 + ty + 8 * m, i0 + tx, DIM);
    H[o] = h;
    if (L) L[o] = f2bf(v - bf2f(h));
  }
}

// z=0: Q = X Wq (split, packed out)  z=1: K likewise
// z=2: VT = Wv^T X^T (bf16, packed out, rows over DIM, Kd=SEQ)
__global__ __launch_bounds__(256) void qkv_kernel(
    const u16* __restrict__ Xh, const u16* __restrict__ Xl,
    const u16* __restrict__ Wh0, const u16* __restrict__ Wl0,
    const u16* __restrict__ Wh1, const u16* __restrict__ Wl1,
    const u16* __restrict__ Wh2,
    u16* __restrict__ Qh, u16* __restrict__ Ql,
    u16* __restrict__ Kh, u16* __restrict__ Kl,
    u16* __restrict__ VT) {
  __shared__ __align__(16) u16 lds[4 * 4096];
  const int z = blockIdx.z;
  f32x4 acc[4][4];
  if (z < 2) {
    const u16* Wh = z ? Wh1 : Wh0;
    const u16* Wl = z ? Wl1 : Wl0;
    const int row0 = blockIdx.y * 128, col0 = blockIdx.x * 128;
    gemm_multi_pk<3>(Xh + (size_t)row0 * DIM, Xl + (size_t)row0 * DIM,
                     Wh + (size_t)col0 * DIM, Wl + (size_t)col0 * DIM,
                     DIM / 32, lds, acc);
    EPILOGUE_IDX
    u16* H = z ? Kh : Qh;
    u16* L = z ? Kl : Ql;
#pragma unroll
    for (int mi = 0; mi < 4; ++mi)
#pragma unroll
      for (int ni = 0; ni < 4; ++ni)
#pragma unroll
        for (int r = 0; r < 4; ++r) {
          int row = row0 + wm * 64 + mi * 16 + q * 4 + r;
          int col = col0 + wn * 64 + ni * 16 + lr;
          float v = acc[mi][ni][r];
          u16 h = f2bf(v);
          size_t o = pkoff(row, col, DIM);
          H[o] = h;
          L[o] = f2bf(v - bf2f(h));
        }
  } else {
    const int row0 = blockIdx.x * 128;  // over DIM
    const int col0 = blockIdx.y * 128;  // over SEQ
    gemm_one64(Wh2 + (size_t)row0 * DIM, Xh + (size_t)col0 * DIM,
               DIM / 32, lds, acc);
    EPILOGUE_IDX
#pragma unroll
    for (int mi = 0; mi < 4; ++mi)
#pragma unroll
      for (int ni = 0; ni < 4; ++ni)
#pragma unroll
        for (int r = 0; r < 4; ++r) {
          int row = row0 + wm * 64 + mi * 16 + q * 4 + r;
          int col = col0 + wn * 64 + ni * 16 + lr;
          VT[pkoff(row, col, SEQ)] = f2bf(acc[mi][ni][r]);
        }
  }
}

// S = (Q K^T) * 1/32, split-precision fused 3-pair, fp32 row-major out
__global__ __launch_bounds__(256) void s_kernel(
    const u16* __restrict__ Qh, const u16* __restrict__ Ql,
    const u16* __restrict__ Kh, const u16* __restrict__ Kl,
    float* __restrict__ S) {
  __shared__ __align__(16) u16 lds[4 * 4096];
  const int row0 = blockIdx.y * 128, col0 = blockIdx.x * 128;
  f32x4 acc[4][4];
  gemm_multi_pk<3>(Qh + (size_t)row0 * DIM, Ql + (size_t)row0 * DIM,
                   Kh + (size_t)col0 * DIM, Kl + (size_t)col0 * DIM,
                   DIM / 32, lds, acc);
  EPILOGUE_IDX
  const float scale = 0.03125f;  // 1/sqrt(1024)
#pragma unroll
  for (int mi = 0; mi < 4; ++mi)
#pragma unroll
    for (int ni = 0; ni < 4; ++ni)
#pragma unroll
      for (int r = 0; r < 4; ++r) {
        int row = row0 + wm * 64 + mi * 16 + q * 4 + r;
        int col = col0 + wn * 64 + ni * 16 + lr;
        S[(size_t)row * SEQ + col] = acc[mi][ni][r] * scale;
      }
}

// row softmax: S fp32 [4096][4096] -> P bf16 tile-packed (Kd=SEQ)
__global__ __launch_bounds__(256) void softmax_kernel(const float* __restrict__ S,
                                                      u16* __restrict__ P) {
  const int row = blockIdx.x;
  const float* s = S + (size_t)row * SEQ;
  const int tid = threadIdx.x;
  float v[16];
  float mx = -3.4e38f;
#pragma unroll
  for (int i = 0; i < 16; ++i) {
    v[i] = s[tid + i * 256];
    mx = fmaxf(mx, v[i]);
  }
#pragma unroll
  for (int off = 32; off; off >>= 1) mx = fmaxf(mx, __shfl_xor(mx, off));
  __shared__ float red[8];
  const int w = tid >> 6, l = tid & 63;
  if (l == 0) red[w] = mx;
  __syncthreads();
  mx = fmaxf(fmaxf(red[0], red[1]), fmaxf(red[2], red[3]));
  float sum = 0.f;
#pragma unroll
  for (int i = 0; i < 16; ++i) {
    v[i] = __expf(v[i] - mx);
    sum += v[i];
  }
#pragma unroll
  for (int off = 32; off; off >>= 1) sum += __shfl_xor(sum, off);
  if (l == 0) red[4 + w] = sum;
  __syncthreads();
  sum = red[4] + red[5] + red[6] + red[7];
  const float inv = 1.f / sum;
#pragma unroll
  for (int i = 0; i < 16; ++i)
    P[pkoff(row, tid + i * 256, SEQ)] = f2bf(v[i] * inv);
}

// O partial = P[:, z*1024:(z+1)*1024] @ V[...]  (split-K=4, packed operands, BK=64)
__global__ __launch_bounds__(256) void o_kernel(const u16* __restrict__ P,
                                                const u16* __restrict__ VT,
                                                float* __restrict__ Opart) {
  __shared__ __align__(16) u16 lds[4 * 4096];
  const int z = blockIdx.z;
  const int row0 = blockIdx.y * 128, col0 = blockIdx.x * 128;
  const u16* A = P + (size_t)row0 * SEQ + (size_t)z * 32 * 4096;
  const u16* B = VT + (size_t)col0 * SEQ + (size_t)z * 32 * 4096;
  f32x4 acc[4][4];
  gemm_one64(A, B, 32, lds, acc);
  EPILOGUE_IDX
  float* O = Opart + (size_t)z * SEQ * DIM;
#pragma unroll
  for (int mi = 0; mi < 4; ++mi)
#pragma unroll
    for (int ni = 0; ni < 4; ++ni)
#pragma unroll
      for (int r = 0; r < 4; ++r) {
        int row = row0 + wm * 64 + mi * 16 + q * 4 + r;
        int col = col0 + wn * 64 + ni * 16 + lr;
        O[(size_t)row * DIM + col] = acc[mi][ni][r];
      }
}

__global__ __launch_bounds__(256) void o_reduce_kernel(const float* __restrict__ Op,
                                                       float* __restrict__ O) {
  const size_t N = (size_t)SEQ * DIM;
  size_t i = ((size_t)blockIdx.x * 256 + threadIdx.x) * 4;
  float4 a = *(const float4*)(Op + i);
  float4 b = *(const float4*)(Op + N + i);
  float4 c = *(const float4*)(Op + 2 * N + i);
  float4 d = *(const float4*)(Op + 3 * N + i);
  float4 r;
  r.x = (a.x + b.x) + (c.x + d.x);
  r.y = (a.y + b.y) + (c.y + d.y);
  r.z = (a.z + b.z) + (c.z + d.z);
  r.w = (a.w + b.w) + (c.w + d.w);
  *(float4*)(O + i) = r;
}

// ---------- launch ----------
extern "C" void kernel_launch(void* const* d_in, const int* in_sizes, int n_in,
                              void* d_out, int out_size, void* d_ws, size_t ws_size,
                              hipStream_t stream) {
  const float* X = (const float*)d_in[0];
  const float* Wq = (const float*)d_in[1];
  const float* Wk = (const float*)d_in[2];
  const float* Wv = (const float*)d_in[3];

  const size_t MB = 1024 * 1024;
  char* w = (char*)d_ws;
  u16* Xh = (u16*)(w + 0 * MB);    // 8 MB
  u16* Xl = (u16*)(w + 8 * MB);    // 8 MB
  u16* WqhT = (u16*)(w + 16 * MB); // 2 MB each
  u16* WqlT = (u16*)(w + 18 * MB);
  u16* WkhT = (u16*)(w + 20 * MB);
  u16* WklT = (u16*)(w + 22 * MB);
  u16* WvhT = (u16*)(w + 24 * MB);
  u16* Qh = (u16*)(w + 26 * MB);   // 8 MB each
  u16* Ql = (u16*)(w + 34 * MB);
  u16* Kh = (u16*)(w + 42 * MB);
  u16* Kl = (u16*)(w + 50 * MB);
  u16* VT = (u16*)(w + 58 * MB);   // 8 MB
  float* S = (float*)(w + 66 * MB);    // 64 MB
  u16* P = (u16*)(w + 26 * MB);        // aliases Qh..Kl (dead after s_kernel)
  float* Opart = (float*)(w + 66 * MB);// aliases S (dead after softmax), 64 MB
  // total: 130 MB

  prep_kernel<<<dim3(32, 32, 4), dim3(32, 8), 0, stream>>>(
      X, Wq, Wk, Wv, Xh, Xl, WqhT, WqlT, WkhT, WklT, WvhT);
  qkv_kernel<<<dim3(DIM / 128, SEQ / 128, 3), 256, 0, stream>>>(
      Xh, Xl, WqhT, WqlT, WkhT, WklT, WvhT, Qh, Ql, Kh, Kl, VT);
  s_kernel<<<dim3(SEQ / 128, SEQ / 128), 256, 0, stream>>>(Qh, Ql, Kh, Kl, S);
  softmax_kernel<<<SEQ, 256, 0, stream>>>(S, P);
  o_kernel<<<dim3(DIM / 128, SEQ / 128, 4), 256, 0, stream>>>(P, VT, Opart);
  o_reduce_kernel<<<(SEQ * DIM) / (256 * 4), 256, 0, stream>>>(Opart, (float*)d_out);
}

// Round 5
// 337.812 us; speedup vs baseline: 1.1821x; 1.0083x over previous
//
#include <hip/hip_runtime.h>

typedef unsigned short u16;
typedef __attribute__((ext_vector_type(8))) short bf16x8;
typedef __attribute__((ext_vector_type(16))) float f32x16;

#define SEQ 4096
#define DIM 1024

// ---------- bf16 helpers (OCP bf16 = top 16 bits of fp32, RNE) ----------
__device__ __forceinline__ u16 f2bf(float f) {
  unsigned u = __float_as_uint(f);
  return (u16)((u + 0x7fffu + ((u >> 16) & 1u)) >> 16);
}
__device__ __forceinline__ float bf2f(u16 h) {
  return __uint_as_float(((unsigned)h) << 16);
}

// ---------- async global->LDS, 16B per lane ----------
__device__ __forceinline__ void gload_lds16(const void* g, void* l) {
  __builtin_amdgcn_global_load_lds(
      (const __attribute__((address_space(1))) void*)g,
      (__attribute__((address_space(3))) void*)l, 16, 0, 0);
}

// ---------- tile-packed operand layout (r4-verified: 0 bank conflicts) ----------
// Matrix [R][Kd] stored as 128x32 tiles; tile (rb,kb) at (rb*(Kd/32)+kb)*4096.
// Within tile, 16B slot s = ((r7>>4)<<6) | ((c5>>3)<<4) | (r7&15), elem = c5&7.
// Staging reads are perfectly lane-contiguous (1KB/instr); fragment reads are
// lane-linear 16B (16x16 frags) or 256B-per-quarter-wave (32x32 frags) — both
// conflict-free.
__device__ __forceinline__ size_t pkoff(int row, int col, int kd) {
  int tile = (row >> 7) * (kd >> 5) + (col >> 5);
  int r7 = row & 127, c5 = col & 31;
  int slot = ((r7 >> 4) << 6) | ((c5 >> 3) << 4) | (r7 & 15);
  return (size_t)tile * 4096 + (size_t)(slot * 8 + (c5 & 7));
}

// stage one packed 128x32 tile (4096 elems, contiguous) into LDS
__device__ __forceinline__ void stage_tile_pk(const u16* __restrict__ g,
                                              u16* lds, int tid) {
  const int w = tid >> 6;
  gload_lds16(g + (size_t)tid * 8, lds + (size_t)(w * 64) * 8);
  gload_lds16(g + (size_t)(256 + tid) * 8, lds + (size_t)(256 + w * 64) * 8);
}

// ---------- 32x32x16 fragment addressing ----------
// A-frag (NT, both operands): lane l holds rows m = msub*32 + (l&31),
// k = ks*16 + (l>>5)*8 + j.  In packed tile: elem offset =
//   opbase + wm*2048 + msub*1024 + ks*256 + lbase,
//   lbase = ((l&31)>>4)*512 + (l>>5)*128 + (l&15)*8.
// C/D layout (m74/m101 verified): col = l&31, row = (reg&3)+8*(reg>>2)+4*(l>>5).
#define MFMA32(a, b, c) __builtin_amdgcn_mfma_f32_32x32x16_bf16((a), (b), (c), 0, 0, 0)

// ---------- fused multi-pair NT GEMM core (packed operands, BK=32) ----------
// C[128,128] += A0*B0^T (+ A0*B1^T + A1*B0^T for NPAIR==3)
// 4 waves 2x2; wave computes 64x64 as 2x2 of 32x32x16 MFMA, 2 k-steps/tile.
template <int NPAIR>
__device__ __forceinline__ void gemm_multi_pk(
    const u16* A0, const u16* A1, const u16* B0, const u16* B1,
    int nkb, u16* lds, f32x16 (&acc)[2][2]) {
  const int tid = threadIdx.x;
  const int w = tid >> 6, l = tid & 63;
  const int wm = w >> 1, wn = w & 1;
  const int lbase = ((l & 31) >> 4) * 512 + (l >> 5) * 128 + (l & 15) * 8;
  u16* lA0 = lds;
  u16* lB0 = lds + 4096;
  u16* lA1 = lds + 8192;
  u16* lB1 = lds + 12288;

#pragma unroll
  for (int ms = 0; ms < 2; ++ms)
#pragma unroll
    for (int ns = 0; ns < 2; ++ns)
#pragma unroll
      for (int i = 0; i < 16; ++i) acc[ms][ns][i] = 0.f;

  const int ao = wm * 2048 + lbase;
  const int bo = wn * 2048 + lbase;

  for (int kb = 0; kb < nkb; ++kb) {
    stage_tile_pk(A0 + (size_t)kb * 4096, lA0, tid);
    stage_tile_pk(B0 + (size_t)kb * 4096, lB0, tid);
    if constexpr (NPAIR >= 3) {
      stage_tile_pk(A1 + (size_t)kb * 4096, lA1, tid);
      stage_tile_pk(B1 + (size_t)kb * 4096, lB1, tid);
    }
    __syncthreads();
    bf16x8 a0[2][2], b0[2][2];
#pragma unroll
    for (int ms = 0; ms < 2; ++ms)
#pragma unroll
      for (int ks = 0; ks < 2; ++ks) {
        a0[ms][ks] = *(const bf16x8*)(lA0 + ao + ms * 1024 + ks * 256);
        b0[ms][ks] = *(const bf16x8*)(lB0 + bo + ms * 1024 + ks * 256);
      }
#pragma unroll
    for (int ms = 0; ms < 2; ++ms)
#pragma unroll
      for (int ns = 0; ns < 2; ++ns)
#pragma unroll
        for (int ks = 0; ks < 2; ++ks)
          acc[ms][ns] = MFMA32(a0[ms][ks], b0[ns][ks], acc[ms][ns]);
    if constexpr (NPAIR >= 3) {
      bf16x8 b1[2][2];
#pragma unroll
      for (int ns = 0; ns < 2; ++ns)
#pragma unroll
        for (int ks = 0; ks < 2; ++ks)
          b1[ns][ks] = *(const bf16x8*)(lB1 + bo + ns * 1024 + ks * 256);
#pragma unroll
      for (int ms = 0; ms < 2; ++ms)
#pragma unroll
        for (int ns = 0; ns < 2; ++ns)
#pragma unroll
          for (int ks = 0; ks < 2; ++ks)
            acc[ms][ns] = MFMA32(a0[ms][ks], b1[ns][ks], acc[ms][ns]);
      bf16x8 a1[2][2];
#pragma unroll
      for (int ms = 0; ms < 2; ++ms)
#pragma unroll
        for (int ks = 0; ks < 2; ++ks)
          a1[ms][ks] = *(const bf16x8*)(lA1 + ao + ms * 1024 + ks * 256);
#pragma unroll
      for (int ms = 0; ms < 2; ++ms)
#pragma unroll
        for (int ns = 0; ns < 2; ++ns)
#pragma unroll
          for (int ks = 0; ks < 2; ++ks)
            acc[ms][ns] = MFMA32(a1[ms][ks], b0[ns][ks], acc[ms][ns]);
    }
    __syncthreads();
  }
}

// ---------- single-pair NT GEMM core, BK=64 (two packed tiles/barrier) ----------
__device__ __forceinline__ void gemm_one64(
    const u16* A, const u16* B, int nkb, u16* lds, f32x16 (&acc)[2][2]) {
  const int tid = threadIdx.x;
  const int w = tid >> 6, l = tid & 63;
  const int wm = w >> 1, wn = w & 1;
  const int lbase = ((l & 31) >> 4) * 512 + (l >> 5) * 128 + (l & 15) * 8;
  u16* lA = lds;          // 2 tiles
  u16* lB = lds + 8192;   // 2 tiles

#pragma unroll
  for (int ms = 0; ms < 2; ++ms)
#pragma unroll
    for (int ns = 0; ns < 2; ++ns)
#pragma unroll
      for (int i = 0; i < 16; ++i) acc[ms][ns][i] = 0.f;

  const int ao = wm * 2048 + lbase;
  const int bo = wn * 2048 + lbase;

  for (int kb = 0; kb < nkb; kb += 2) {
    stage_tile_pk(A + (size_t)kb * 4096, lA, tid);
    stage_tile_pk(A + (size_t)(kb + 1) * 4096, lA + 4096, tid);
    stage_tile_pk(B + (size_t)kb * 4096, lB, tid);
    stage_tile_pk(B + (size_t)(kb + 1) * 4096, lB + 4096, tid);
    __syncthreads();
#pragma unroll
    for (int ht = 0; ht < 2; ++ht) {
      bf16x8 av[2][2], bv[2][2];
#pragma unroll
      for (int ms = 0; ms < 2; ++ms)
#pragma unroll
        for (int ks = 0; ks < 2; ++ks) {
          av[ms][ks] = *(const bf16x8*)(lA + ht * 4096 + ao + ms * 1024 + ks * 256);
          bv[ms][ks] = *(const bf16x8*)(lB + ht * 4096 + bo + ms * 1024 + ks * 256);
        }
#pragma unroll
      for (int ms = 0; ms < 2; ++ms)
#pragma unroll
        for (int ns = 0; ns < 2; ++ns)
#pragma unroll
          for (int ks = 0; ks < 2; ++ks)
            acc[ms][ns] = MFMA32(av[ms][ks], bv[ns][ks], acc[ms][ns]);
    }
    __syncthreads();
  }
}

// 32x32 C/D epilogue indices
#define EPILOGUE_IDX32                                     \
  const int tid = threadIdx.x, w = tid >> 6, l = tid & 63; \
  const int wm = w >> 1, wn = w & 1, r = l & 31, h = l >> 5; (void)tid;

// ---------- kernels ----------

// z=0: X fp32 -> hi/lo bf16, tile-packed (Kd=DIM)
// z=1..3: W fp32 [in][out] -> W^T bf16 [out][in] tile-packed; hi/lo for Wq,Wk, hi for Wv
__global__ __launch_bounds__(256) void prep_kernel(
    const float* __restrict__ X,
    const float* __restrict__ W0, const float* __restrict__ W1, const float* __restrict__ W2,
    u16* __restrict__ Xh, u16* __restrict__ Xl,
    u16* __restrict__ H0, u16* __restrict__ L0,
    u16* __restrict__ H1, u16* __restrict__ L1,
    u16* __restrict__ H2) {
  const int z = blockIdx.z;
  const int tx = threadIdx.x, ty = threadIdx.y;
  if (z == 0) {
    int idx = (blockIdx.y * 32 + blockIdx.x) * 256 + ty * 32 + tx;
    int row = idx >> 6;
    int c0 = (idx & 63) * 16;
    bf16x8 h0, h1, l0v, l1v;
#pragma unroll
    for (int j = 0; j < 4; ++j) {
      float4 x = *(const float4*)(X + (size_t)row * DIM + c0 + j * 4);
      u16 hh, ll;
      float v;
      v = x.x; hh = f2bf(v); ll = f2bf(v - bf2f(hh));
      if (j < 2) { h0[j*4+0] = (short)hh; l0v[j*4+0] = (short)ll; } else { h1[(j-2)*4+0] = (short)hh; l1v[(j-2)*4+0] = (short)ll; }
      v = x.y; hh = f2bf(v); ll = f2bf(v - bf2f(hh));
      if (j < 2) { h0[j*4+1] = (short)hh; l0v[j*4+1] = (short)ll; } else { h1[(j-2)*4+1] = (short)hh; l1v[(j-2)*4+1] = (short)ll; }
      v = x.z; hh = f2bf(v); ll = f2bf(v - bf2f(hh));
      if (j < 2) { h0[j*4+2] = (short)hh; l0v[j*4+2] = (short)ll; } else { h1[(j-2)*4+2] = (short)hh; l1v[(j-2)*4+2] = (short)ll; }
      v = x.w; hh = f2bf(v); ll = f2bf(v - bf2f(hh));
      if (j < 2) { h0[j*4+3] = (short)hh; l0v[j*4+3] = (short)ll; } else { h1[(j-2)*4+3] = (short)hh; l1v[(j-2)*4+3] = (short)ll; }
    }
    size_t o0 = pkoff(row, c0, DIM);
    size_t o1 = pkoff(row, c0 + 8, DIM);
    *(bf16x8*)(Xh + o0) = h0;
    *(bf16x8*)(Xl + o0) = l0v;
    *(bf16x8*)(Xh + o1) = h1;
    *(bf16x8*)(Xl + o1) = l1v;
    return;
  }
  __shared__ float t[32][33];
  const float* W = (z == 1) ? W0 : (z == 2) ? W1 : W2;
  u16* H = (z == 1) ? H0 : (z == 2) ? H1 : H2;
  u16* L = (z == 1) ? L0 : (z == 2) ? L1 : nullptr;
  const int i0 = blockIdx.y * 32, o0 = blockIdx.x * 32;
#pragma unroll
  for (int m = 0; m < 4; ++m)
    t[ty + 8 * m][tx] = W[(size_t)(i0 + ty + 8 * m) * DIM + o0 + tx];
  __syncthreads();
#pragma unroll
  for (int m = 0; m < 4; ++m) {
    float v = t[tx][ty + 8 * m];
    u16 h = f2bf(v);
    size_t o = pkoff(o0 + ty + 8 * m, i0 + tx, DIM);
    H[o] = h;
    if (L) L[o] = f2bf(v - bf2f(h));
  }
}

// z=0: Q = X Wq (split, packed out)  z=1: K likewise
// z=2: VT = Wv^T X^T (bf16, packed out, rows over DIM, Kd=SEQ)
__global__ __launch_bounds__(256) void qkv_kernel(
    const u16* __restrict__ Xh, const u16* __restrict__ Xl,
    const u16* __restrict__ Wh0, const u16* __restrict__ Wl0,
    const u16* __restrict__ Wh1, const u16* __restrict__ Wl1,
    const u16* __restrict__ Wh2,
    u16* __restrict__ Qh, u16* __restrict__ Ql,
    u16* __restrict__ Kh, u16* __restrict__ Kl,
    u16* __restrict__ VT) {
  __shared__ __align__(16) u16 lds[4 * 4096];
  const int z = blockIdx.z;
  f32x16 acc[2][2];
  if (z < 2) {
    const u16* Wh = z ? Wh1 : Wh0;
    const u16* Wl = z ? Wl1 : Wl0;
    const int row0 = blockIdx.y * 128, col0 = blockIdx.x * 128;
    gemm_multi_pk<3>(Xh + (size_t)row0 * DIM, Xl + (size_t)row0 * DIM,
                     Wh + (size_t)col0 * DIM, Wl + (size_t)col0 * DIM,
                     DIM / 32, lds, acc);
    EPILOGUE_IDX32
    u16* H = z ? Kh : Qh;
    u16* L = z ? Kl : Ql;
#pragma unroll
    for (int ms = 0; ms < 2; ++ms)
#pragma unroll
      for (int ns = 0; ns < 2; ++ns)
#pragma unroll
        for (int reg = 0; reg < 16; ++reg) {
          int row = row0 + wm * 64 + ms * 32 + (reg & 3) + 8 * (reg >> 2) + 4 * h;
          int col = col0 + wn * 64 + ns * 32 + r;
          float v = acc[ms][ns][reg];
          u16 hh = f2bf(v);
          size_t o = pkoff(row, col, DIM);
          H[o] = hh;
          L[o] = f2bf(v - bf2f(hh));
        }
  } else {
    const int row0 = blockIdx.x * 128;  // over DIM
    const int col0 = blockIdx.y * 128;  // over SEQ
    gemm_one64(Wh2 + (size_t)row0 * DIM, Xh + (size_t)col0 * DIM,
               DIM / 32, lds, acc);
    EPILOGUE_IDX32
#pragma unroll
    for (int ms = 0; ms < 2; ++ms)
#pragma unroll
      for (int ns = 0; ns < 2; ++ns)
#pragma unroll
        for (int reg = 0; reg < 16; ++reg) {
          int row = row0 + wm * 64 + ms * 32 + (reg & 3) + 8 * (reg >> 2) + 4 * h;
          int col = col0 + wn * 64 + ns * 32 + r;
          VT[pkoff(row, col, SEQ)] = f2bf(acc[ms][ns][reg]);
        }
  }
}

// S = (Q K^T) * 1/32, split-precision fused 3-pair, fp32 row-major out
__global__ __launch_bounds__(256) void s_kernel(
    const u16* __restrict__ Qh, const u16* __restrict__ Ql,
    const u16* __restrict__ Kh, const u16* __restrict__ Kl,
    float* __restrict__ S) {
  __shared__ __align__(16) u16 lds[4 * 4096];
  const int row0 = blockIdx.y * 128, col0 = blockIdx.x * 128;
  f32x16 acc[2][2];
  gemm_multi_pk<3>(Qh + (size_t)row0 * DIM, Ql + (size_t)row0 * DIM,
                   Kh + (size_t)col0 * DIM, Kl + (size_t)col0 * DIM,
                   DIM / 32, lds, acc);
  EPILOGUE_IDX32
  const float scale = 0.03125f;  // 1/sqrt(1024)
#pragma unroll
  for (int ms = 0; ms < 2; ++ms)
#pragma unroll
    for (int ns = 0; ns < 2; ++ns)
#pragma unroll
      for (int reg = 0; reg < 16; ++reg) {
        int row = row0 + wm * 64 + ms * 32 + (reg & 3) + 8 * (reg >> 2) + 4 * h;
        int col = col0 + wn * 64 + ns * 32 + r;
        S[(size_t)row * SEQ + col] = acc[ms][ns][reg] * scale;
      }
}

// row softmax: S fp32 [4096][4096] -> P bf16 tile-packed (Kd=SEQ)
// Thread t owns 16 consecutive cols -> 4x float4 loads, 2x 16B packed stores.
__global__ __launch_bounds__(256) void softmax_kernel(const float* __restrict__ S,
                                                      u16* __restrict__ P) {
  const int row = blockIdx.x;
  const float* s = S + (size_t)row * SEQ;
  const int tid = threadIdx.x;
  const int c0 = tid * 16;
  float v[16];
  float mx = -3.4e38f;
#pragma unroll
  for (int j = 0; j < 4; ++j) {
    float4 x = *(const float4*)(s + c0 + j * 4);
    v[j * 4 + 0] = x.x; v[j * 4 + 1] = x.y; v[j * 4 + 2] = x.z; v[j * 4 + 3] = x.w;
    mx = fmaxf(mx, fmaxf(fmaxf(x.x, x.y), fmaxf(x.z, x.w)));
  }
#pragma unroll
  for (int off = 32; off; off >>= 1) mx = fmaxf(mx, __shfl_xor(mx, off));
  __shared__ float red[8];
  const int w = tid >> 6, l = tid & 63;
  if (l == 0) red[w] = mx;
  __syncthreads();
  mx = fmaxf(fmaxf(red[0], red[1]), fmaxf(red[2], red[3]));
  float sum = 0.f;
#pragma unroll
  for (int i = 0; i < 16; ++i) {
    v[i] = __expf(v[i] - mx);
    sum += v[i];
  }
#pragma unroll
  for (int off = 32; off; off >>= 1) sum += __shfl_xor(sum, off);
  if (l == 0) red[4 + w] = sum;
  __syncthreads();
  sum = red[4] + red[5] + red[6] + red[7];
  const float inv = 1.f / sum;
  bf16x8 p0, p1;
#pragma unroll
  for (int i = 0; i < 8; ++i) {
    p0[i] = (short)f2bf(v[i] * inv);
    p1[i] = (short)f2bf(v[8 + i] * inv);
  }
  *(bf16x8*)(P + pkoff(row, c0, SEQ)) = p0;
  *(bf16x8*)(P + pkoff(row, c0 + 8, SEQ)) = p1;
}

// O partial = P[:, z*1024:(z+1)*1024] @ V[...]  (split-K=4, packed operands, BK=64)
__global__ __launch_bounds__(256) void o_kernel(const u16* __restrict__ P,
                                                const u16* __restrict__ VT,
                                                float* __restrict__ Opart) {
  __shared__ __align__(16) u16 lds[4 * 4096];
  const int z = blockIdx.z;
  const int row0 = blockIdx.y * 128, col0 = blockIdx.x * 128;
  const u16* A = P + (size_t)row0 * SEQ + (size_t)z * 32 * 4096;
  const u16* B = VT + (size_t)col0 * SEQ + (size_t)z * 32 * 4096;
  f32x16 acc[2][2];
  gemm_one64(A, B, 32, lds, acc);
  EPILOGUE_IDX32
  float* O = Opart + (size_t)z * SEQ * DIM;
#pragma unroll
  for (int ms = 0; ms < 2; ++ms)
#pragma unroll
    for (int ns = 0; ns < 2; ++ns)
#pragma unroll
      for (int reg = 0; reg < 16; ++reg) {
        int row = row0 + wm * 64 + ms * 32 + (reg & 3) + 8 * (reg >> 2) + 4 * h;
        int col = col0 + wn * 64 + ns * 32 + r;
        O[(size_t)row * DIM + col] = acc[ms][ns][reg];
      }
}

__global__ __launch_bounds__(256) void o_reduce_kernel(const float* __restrict__ Op,
                                                       float* __restrict__ O) {
  const size_t N = (size_t)SEQ * DIM;
  size_t i = ((size_t)blockIdx.x * 256 + threadIdx.x) * 4;
  float4 a = *(const float4*)(Op + i);
  float4 b = *(const float4*)(Op + N + i);
  float4 c = *(const float4*)(Op + 2 * N + i);
  float4 d = *(const float4*)(Op + 3 * N + i);
  float4 rr;
  rr.x = (a.x + b.x) + (c.x + d.x);
  rr.y = (a.y + b.y) + (c.y + d.y);
  rr.z = (a.z + b.z) + (c.z + d.z);
  rr.w = (a.w + b.w) + (c.w + d.w);
  *(float4*)(O + i) = rr;
}

// ---------- launch ----------
extern "C" void kernel_launch(void* const* d_in, const int* in_sizes, int n_in,
                              void* d_out, int out_size, void* d_ws, size_t ws_size,
                              hipStream_t stream) {
  const float* X = (const float*)d_in[0];
  const float* Wq = (const float*)d_in[1];
  const float* Wk = (const float*)d_in[2];
  const float* Wv = (const float*)d_in[3];

  const size_t MB = 1024 * 1024;
  char* w = (char*)d_ws;
  u16* Xh = (u16*)(w + 0 * MB);    // 8 MB
  u16* Xl = (u16*)(w + 8 * MB);    // 8 MB
  u16* WqhT = (u16*)(w + 16 * MB); // 2 MB each
  u16* WqlT = (u16*)(w + 18 * MB);
  u16* WkhT = (u16*)(w + 20 * MB);
  u16* WklT = (u16*)(w + 22 * MB);
  u16* WvhT = (u16*)(w + 24 * MB);
  u16* Qh = (u16*)(w + 26 * MB);   // 8 MB each
  u16* Ql = (u16*)(w + 34 * MB);
  u16* Kh = (u16*)(w + 42 * MB);
  u16* Kl = (u16*)(w + 50 * MB);
  u16* VT = (u16*)(w + 58 * MB);   // 8 MB
  float* S = (float*)(w + 66 * MB);    // 64 MB
  u16* P = (u16*)(w + 26 * MB);        // aliases Qh..Kl (dead after s_kernel)
  float* Opart = (float*)(w + 66 * MB);// aliases S (dead after softmax), 64 MB
  // total: 130 MB

  prep_kernel<<<dim3(32, 32, 4), dim3(32, 8), 0, stream>>>(
      X, Wq, Wk, Wv, Xh, Xl, WqhT, WqlT, WkhT, WklT, WvhT);
  qkv_kernel<<<dim3(DIM / 128, SEQ / 128, 3), 256, 0, stream>>>(
      Xh, Xl, WqhT, WqlT, WkhT, WklT, WvhT, Qh, Ql, Kh, Kl, VT);
  s_kernel<<<dim3(SEQ / 128, SEQ / 128), 256, 0, stream>>>(Qh, Ql, Kh, Kl, S);
  softmax_kernel<<<SEQ, 256, 0, stream>>>(S, P);
  o_kernel<<<dim3(DIM / 128, SEQ / 128, 4), 256, 0, stream>>>(P, VT, Opart);
  o_reduce_kernel<<<(SEQ * DIM) / (256 * 4), 256, 0, stream>>>(Opart, (float*)d_out);
}

// Round 7
// 317.926 us; speedup vs baseline: 1.2560x; 1.0625x over previous
//
#include <hip/hip_runtime.h>

typedef unsigned short u16;
typedef __attribute__((ext_vector_type(8))) short bf16x8;
typedef __attribute__((ext_vector_type(4))) float f32x4;

#define SEQ 4096
#define DIM 1024

// ---------- bf16 helpers (OCP bf16 = top 16 bits of fp32, RNE) ----------
__device__ __forceinline__ u16 f2bf(float f) {
  unsigned u = __float_as_uint(f);
  return (u16)((u + 0x7fffu + ((u >> 16) & 1u)) >> 16);
}
__device__ __forceinline__ float bf2f(u16 h) {
  return __uint_as_float(((unsigned)h) << 16);
}

// ---------- async global->LDS, 16B per lane ----------
__device__ __forceinline__ void gload_lds16(const void* g, void* l) {
  __builtin_amdgcn_global_load_lds(
      (const __attribute__((address_space(1))) void*)g,
      (__attribute__((address_space(3))) void*)l, 16, 0, 0);
}

// ---------- tile-packed operand layout (r4-verified: 0 bank conflicts) ----------
// Matrix [R][Kd] stored as 128x32 tiles; tile (rb,kb) at (rb*(Kd/32)+kb)*4096.
// Within tile, 16B slot s = ((r7>>4)<<6) | ((c5>>3)<<4) | (r7&15), elem = c5&7.
// Staging reads are perfectly lane-contiguous (1KB/instr); 16x16 fragment reads
// are lane-linear 16B — both conflict-free (r4: SQ_LDS_BANK_CONFLICT == 0).
__device__ __forceinline__ size_t pkoff(int row, int col, int kd) {
  int tile = (row >> 7) * (kd >> 5) + (col >> 5);
  int r7 = row & 127, c5 = col & 31;
  int slot = ((r7 >> 4) << 6) | ((c5 >> 3) << 4) | (r7 & 15);
  return (size_t)tile * 4096 + (size_t)(slot * 8 + (c5 & 7));
}

// stage one packed 128x32 tile (4096 elems, contiguous) into LDS
__device__ __forceinline__ void stage_tile_pk(const u16* __restrict__ g,
                                              u16* lds, int tid) {
  const int w = tid >> 6;
  gload_lds16(g + (size_t)tid * 8, lds + (size_t)(w * 64) * 8);
  gload_lds16(g + (size_t)(256 + tid) * 8, lds + (size_t)(256 + w * 64) * 8);
}

// ---------- fused 3-pair NT GEMM core, double-buffered (2 x 32KB LDS) ----------
// C[128,128] += A0*B0^T + A0*B1^T + A1*B0^T.  4 waves 2x2; wave = 4x4 of
// 16x16x32 MFMA (16 independent acc chains — r5 showed 32x32's 4 chains stall).
// One barrier per k-iteration: stage k+1 right after the barrier, compute k's
// 48 MFMAs (~233 cyc) while the loads fly. Safety: each wave's
// lgkmcnt(0)-before-barrier guarantees its ds_reads of buffer b are complete
// before any wave overwrites b two iterations later.
__device__ __forceinline__ void gemm3_db(
    const u16* A0, const u16* A1, const u16* B0, const u16* B1,
    int nkb, u16* lds, f32x4 (&acc)[4][4]) {
  const int tid = threadIdx.x;
  const int w = tid >> 6, l = tid & 63;
  const int wm = w >> 1, wn = w & 1;

#pragma unroll
  for (int mi = 0; mi < 4; ++mi)
#pragma unroll
    for (int ni = 0; ni < 4; ++ni)
      acc[mi][ni] = (f32x4){0.f, 0.f, 0.f, 0.f};

  const int ao = wm * 2048 + l * 8;
  const int bo = wn * 2048 + l * 8;

  // prologue: stage kb=0 into buffer 0
  stage_tile_pk(A0, lds, tid);
  stage_tile_pk(B0, lds + 4096, tid);
  stage_tile_pk(A1, lds + 8192, tid);
  stage_tile_pk(B1, lds + 12288, tid);

  for (int kb = 0; kb < nkb; ++kb) {
    __syncthreads();  // vmcnt(0): buf[kb&1] ready; buf[1-kb&1] free to refill
    if (kb + 1 < nkb) {
      u16* nb = lds + ((kb + 1) & 1) * 16384;
      const size_t off = (size_t)(kb + 1) * 4096;
      stage_tile_pk(A0 + off, nb, tid);
      stage_tile_pk(B0 + off, nb + 4096, tid);
      stage_tile_pk(A1 + off, nb + 8192, tid);
      stage_tile_pk(B1 + off, nb + 12288, tid);
    }
    const u16* cb = lds + (kb & 1) * 16384;
    const u16* lA0 = cb;
    const u16* lB0 = cb + 4096;
    const u16* lA1 = cb + 8192;
    const u16* lB1 = cb + 12288;

    bf16x8 a0[4], b0[4];
#pragma unroll
    for (int i = 0; i < 4; ++i) {
      a0[i] = *(const bf16x8*)(lA0 + ao + i * 512);
      b0[i] = *(const bf16x8*)(lB0 + bo + i * 512);
    }
#pragma unroll
    for (int mi = 0; mi < 4; ++mi)
#pragma unroll
      for (int ni = 0; ni < 4; ++ni)
        acc[mi][ni] = __builtin_amdgcn_mfma_f32_16x16x32_bf16(
            a0[mi], b0[ni], acc[mi][ni], 0, 0, 0);
    bf16x8 b1[4];
#pragma unroll
    for (int i = 0; i < 4; ++i) b1[i] = *(const bf16x8*)(lB1 + bo + i * 512);
#pragma unroll
    for (int mi = 0; mi < 4; ++mi)
#pragma unroll
      for (int ni = 0; ni < 4; ++ni)
        acc[mi][ni] = __builtin_amdgcn_mfma_f32_16x16x32_bf16(
            a0[mi], b1[ni], acc[mi][ni], 0, 0, 0);
    bf16x8 a1[4];
#pragma unroll
    for (int i = 0; i < 4; ++i) a1[i] = *(const bf16x8*)(lA1 + ao + i * 512);
#pragma unroll
    for (int mi = 0; mi < 4; ++mi)
#pragma unroll
      for (int ni = 0; ni < 4; ++ni)
        acc[mi][ni] = __builtin_amdgcn_mfma_f32_16x16x32_bf16(
            a1[mi], b0[ni], acc[mi][ni], 0, 0, 0);
  }
  __syncthreads();
}

// ---------- single-pair NT GEMM core, BK=64, double-buffered (2 x 32KB) ----------
__device__ __forceinline__ void gemm1_db(
    const u16* A, const u16* B, int nkb, u16* lds, f32x4 (&acc)[4][4]) {
  const int tid = threadIdx.x;
  const int w = tid >> 6, l = tid & 63;
  const int wm = w >> 1, wn = w & 1;

#pragma unroll
  for (int mi = 0; mi < 4; ++mi)
#pragma unroll
    for (int ni = 0; ni < 4; ++ni)
      acc[mi][ni] = (f32x4){0.f, 0.f, 0.f, 0.f};

  const int ao = wm * 2048 + l * 8;
  const int bo = wn * 2048 + l * 8;
  const int nit = nkb >> 1;  // BK=64 steps

  // prologue: stage it=0 (tiles kb=0,1) into buffer 0
  stage_tile_pk(A, lds, tid);
  stage_tile_pk(A + 4096, lds + 4096, tid);
  stage_tile_pk(B, lds + 8192, tid);
  stage_tile_pk(B + 4096, lds + 12288, tid);  // FIXED (r6 typo: was B + 8192)

  for (int it = 0; it < nit; ++it) {
    __syncthreads();
    if (it + 1 < nit) {
      u16* nb = lds + ((it + 1) & 1) * 16384;
      const size_t off = (size_t)(it + 1) * 8192;
      stage_tile_pk(A + off, nb, tid);
      stage_tile_pk(A + off + 4096, nb + 4096, tid);
      stage_tile_pk(B + off, nb + 8192, tid);
      stage_tile_pk(B + off + 4096, nb + 12288, tid);
    }
    const u16* cb = lds + (it & 1) * 16384;
#pragma unroll
    for (int ht = 0; ht < 2; ++ht) {
      bf16x8 av[4], bv[4];
#pragma unroll
      for (int i = 0; i < 4; ++i) {
        av[i] = *(const bf16x8*)(cb + ht * 4096 + ao + i * 512);
        bv[i] = *(const bf16x8*)(cb + 8192 + ht * 4096 + bo + i * 512);
      }
#pragma unroll
      for (int mi = 0; mi < 4; ++mi)
#pragma unroll
        for (int ni = 0; ni < 4; ++ni)
          acc[mi][ni] = __builtin_amdgcn_mfma_f32_16x16x32_bf16(
              av[mi], bv[ni], acc[mi][ni], 0, 0, 0);
    }
  }
  __syncthreads();
}

// C/D layout (m89/m91 verified): lane l, reg r -> row=(l>>4)*4+r, col=l&15
#define EPILOGUE_IDX                                          \
  const int tid = threadIdx.x, w = tid >> 6, l = tid & 63;    \
  const int wm = w >> 1, wn = w & 1, lr = l & 15, q = l >> 4; \
  (void)tid;

// ---------- kernels ----------

// z=0: X fp32 -> hi/lo bf16, tile-packed (Kd=DIM)
// z=1..3: W fp32 [in][out] -> W^T bf16 [out][in] tile-packed; hi/lo Wq,Wk; hi Wv
__global__ __launch_bounds__(256) void prep_kernel(
    const float* __restrict__ X,
    const float* __restrict__ W0, const float* __restrict__ W1, const float* __restrict__ W2,
    u16* __restrict__ Xh, u16* __restrict__ Xl,
    u16* __restrict__ H0, u16* __restrict__ L0,
    u16* __restrict__ H1, u16* __restrict__ L1,
    u16* __restrict__ H2) {
  const int z = blockIdx.z;
  const int tx = threadIdx.x, ty = threadIdx.y;
  if (z == 0) {
    int idx = (blockIdx.y * 32 + blockIdx.x) * 256 + ty * 32 + tx;
    int row = idx >> 6;
    int c0 = (idx & 63) * 16;
    u16 h[16], lo[16];
#pragma unroll
    for (int j = 0; j < 4; ++j) {
      float4 x = *(const float4*)(X + (size_t)row * DIM + c0 + j * 4);
      float v;
      v = x.x; h[j*4+0] = f2bf(v); lo[j*4+0] = f2bf(v - bf2f(h[j*4+0]));
      v = x.y; h[j*4+1] = f2bf(v); lo[j*4+1] = f2bf(v - bf2f(h[j*4+1]));
      v = x.z; h[j*4+2] = f2bf(v); lo[j*4+2] = f2bf(v - bf2f(h[j*4+2]));
      v = x.w; h[j*4+3] = f2bf(v); lo[j*4+3] = f2bf(v - bf2f(h[j*4+3]));
    }
    size_t o0 = pkoff(row, c0, DIM);
    size_t o1 = pkoff(row, c0 + 8, DIM);
    *(bf16x8*)(Xh + o0) = *(bf16x8*)(h);
    *(bf16x8*)(Xl + o0) = *(bf16x8*)(lo);
    *(bf16x8*)(Xh + o1) = *(bf16x8*)(h + 8);
    *(bf16x8*)(Xl + o1) = *(bf16x8*)(lo + 8);
    return;
  }
  __shared__ float t[32][33];
  const float* W = (z == 1) ? W0 : (z == 2) ? W1 : W2;
  u16* H = (z == 1) ? H0 : (z == 2) ? H1 : H2;
  u16* L = (z == 1) ? L0 : (z == 2) ? L1 : nullptr;
  const int i0 = blockIdx.y * 32, o0 = blockIdx.x * 32;
#pragma unroll
  for (int m = 0; m < 4; ++m)
    t[ty + 8 * m][tx] = W[(size_t)(i0 + ty + 8 * m) * DIM + o0 + tx];
  __syncthreads();
#pragma unroll
  for (int m = 0; m < 4; ++m) {
    float v = t[tx][ty + 8 * m];
    u16 h = f2bf(v);
    size_t o = pkoff(o0 + ty + 8 * m, i0 + tx, DIM);
    H[o] = h;
    if (L) L[o] = f2bf(v - bf2f(h));
  }
}

// z=0: Q = X Wq (split, packed out)  z=1: K likewise
// z=2: VT = Wv^T X^T (bf16, packed out, rows over DIM, Kd=SEQ)
__global__ __launch_bounds__(256) void qkv_kernel(
    const u16* __restrict__ Xh, const u16* __restrict__ Xl,
    const u16* __restrict__ Wh0, const u16* __restrict__ Wl0,
    const u16* __restrict__ Wh1, const u16* __restrict__ Wl1,
    const u16* __restrict__ Wh2,
    u16* __restrict__ Qh, u16* __restrict__ Ql,
    u16* __restrict__ Kh, u16* __restrict__ Kl,
    u16* __restrict__ VT) {
  __shared__ __align__(16) u16 lds[2 * 4 * 4096];
  const int z = blockIdx.z;
  f32x4 acc[4][4];
  if (z < 2) {
    const u16* Wh = z ? Wh1 : Wh0;
    const u16* Wl = z ? Wl1 : Wl0;
    const int row0 = blockIdx.y * 128, col0 = blockIdx.x * 128;
    gemm3_db(Xh + (size_t)row0 * DIM, Xl + (size_t)row0 * DIM,
             Wh + (size_t)col0 * DIM, Wl + (size_t)col0 * DIM,
             DIM / 32, lds, acc);
    EPILOGUE_IDX
    u16* H = z ? Kh : Qh;
    u16* L = z ? Kl : Ql;
#pragma unroll
    for (int mi = 0; mi < 4; ++mi)
#pragma unroll
      for (int ni = 0; ni < 4; ++ni)
#pragma unroll
        for (int r = 0; r < 4; ++r) {
          int row = row0 + wm * 64 + mi * 16 + q * 4 + r;
          int col = col0 + wn * 64 + ni * 16 + lr;
          float v = acc[mi][ni][r];
          u16 h = f2bf(v);
          size_t o = pkoff(row, col, DIM);
          H[o] = h;
          L[o] = f2bf(v - bf2f(h));
        }
  } else {
    const int row0 = blockIdx.x * 128;  // over DIM
    const int col0 = blockIdx.y * 128;  // over SEQ
    gemm1_db(Wh2 + (size_t)row0 * DIM, Xh + (size_t)col0 * DIM,
             DIM / 32, lds, acc);
    EPILOGUE_IDX
#pragma unroll
    for (int mi = 0; mi < 4; ++mi)
#pragma unroll
      for (int ni = 0; ni < 4; ++ni)
#pragma unroll
        for (int r = 0; r < 4; ++r) {
          int row = row0 + wm * 64 + mi * 16 + q * 4 + r;
          int col = col0 + wn * 64 + ni * 16 + lr;
          VT[pkoff(row, col, SEQ)] = f2bf(acc[mi][ni][r]);
        }
  }
}

// S = (Q K^T) * 1/32, split-precision fused 3-pair, fp32 row-major out
__global__ __launch_bounds__(256) void s_kernel(
    const u16* __restrict__ Qh, const u16* __restrict__ Ql,
    const u16* __restrict__ Kh, const u16* __restrict__ Kl,
    float* __restrict__ S) {
  __shared__ __align__(16) u16 lds[2 * 4 * 4096];
  const int row0 = blockIdx.y * 128, col0 = blockIdx.x * 128;
  f32x4 acc[4][4];
  gemm3_db(Qh + (size_t)row0 * DIM, Ql + (size_t)row0 * DIM,
           Kh + (size_t)col0 * DIM, Kl + (size_t)col0 * DIM,
           DIM / 32, lds, acc);
  EPILOGUE_IDX
  const float scale = 0.03125f;  // 1/sqrt(1024)
#pragma unroll
  for (int mi = 0; mi < 4; ++mi)
#pragma unroll
    for (int ni = 0; ni < 4; ++ni)
#pragma unroll
      for (int r = 0; r < 4; ++r) {
        int row = row0 + wm * 64 + mi * 16 + q * 4 + r;
        int col = col0 + wn * 64 + ni * 16 + lr;
        S[(size_t)row * SEQ + col] = acc[mi][ni][r] * scale;
      }
}

// row softmax: S fp32 [4096][4096] -> P bf16 tile-packed (Kd=SEQ)
// Thread t owns 16 consecutive cols -> 4x float4 loads, 2x 16B packed stores.
__global__ __launch_bounds__(256) void softmax_kernel(const float* __restrict__ S,
                                                      u16* __restrict__ P) {
  const int row = blockIdx.x;
  const float* s = S + (size_t)row * SEQ;
  const int tid = threadIdx.x;
  const int c0 = tid * 16;
  float v[16];
  float mx = -3.4e38f;
#pragma unroll
  for (int j = 0; j < 4; ++j) {
    float4 x = *(const float4*)(s + c0 + j * 4);
    v[j * 4 + 0] = x.x; v[j * 4 + 1] = x.y; v[j * 4 + 2] = x.z; v[j * 4 + 3] = x.w;
    mx = fmaxf(mx, fmaxf(fmaxf(x.x, x.y), fmaxf(x.z, x.w)));
  }
#pragma unroll
  for (int off = 32; off; off >>= 1) mx = fmaxf(mx, __shfl_xor(mx, off));
  __shared__ float red[8];
  const int w = tid >> 6, l = tid & 63;
  if (l == 0) red[w] = mx;
  __syncthreads();
  mx = fmaxf(fmaxf(red[0], red[1]), fmaxf(red[2], red[3]));
  float sum = 0.f;
#pragma unroll
  for (int i = 0; i < 16; ++i) {
    v[i] = __expf(v[i] - mx);
    sum += v[i];
  }
#pragma unroll
  for (int off = 32; off; off >>= 1) sum += __shfl_xor(sum, off);
  if (l == 0) red[4 + w] = sum;
  __syncthreads();
  sum = red[4] + red[5] + red[6] + red[7];
  const float inv = 1.f / sum;
  u16 p[16];
#pragma unroll
  for (int i = 0; i < 16; ++i) p[i] = f2bf(v[i] * inv);
  *(bf16x8*)(P + pkoff(row, c0, SEQ)) = *(bf16x8*)(p);
  *(bf16x8*)(P + pkoff(row, c0 + 8, SEQ)) = *(bf16x8*)(p + 8);
}

// O partial = P[:, z*1024:(z+1)*1024] @ V[...]  (split-K=4, packed, BK=64, dbuf)
__global__ __launch_bounds__(256) void o_kernel(const u16* __restrict__ P,
                                                const u16* __restrict__ VT,
                                                float* __restrict__ Opart) {
  __shared__ __align__(16) u16 lds[2 * 4 * 4096];
  const int z = blockIdx.z;
  const int row0 = blockIdx.y * 128, col0 = blockIdx.x * 128;
  const u16* A = P + (size_t)row0 * SEQ + (size_t)z * 32 * 4096;
  const u16* B = VT + (size_t)col0 * SEQ + (size_t)z * 32 * 4096;
  f32x4 acc[4][4];
  gemm1_db(A, B, 32, lds, acc);
  EPILOGUE_IDX
  float* O = Opart + (size_t)z * SEQ * DIM;
#pragma unroll
  for (int mi = 0; mi < 4; ++mi)
#pragma unroll
    for (int ni = 0; ni < 4; ++ni)
#pragma unroll
      for (int r = 0; r < 4; ++r) {
        int row = row0 + wm * 64 + mi * 16 + q * 4 + r;
        int col = col0 + wn * 64 + ni * 16 + lr;
        O[(size_t)row * DIM + col] = acc[mi][ni][r];
      }
}

__global__ __launch_bounds__(256) void o_reduce_kernel(const float* __restrict__ Op,
                                                       float* __restrict__ O) {
  const size_t N = (size_t)SEQ * DIM;
  size_t i = ((size_t)blockIdx.x * 256 + threadIdx.x) * 4;
  float4 a = *(const float4*)(Op + i);
  float4 b = *(const float4*)(Op + N + i);
  float4 c = *(const float4*)(Op + 2 * N + i);
  float4 d = *(const float4*)(Op + 3 * N + i);
  float4 rr;
  rr.x = (a.x + b.x) + (c.x + d.x);
  rr.y = (a.y + b.y) + (c.y + d.y);
  rr.z = (a.z + b.z) + (c.z + d.z);
  rr.w = (a.w + b.w) + (c.w + d.w);
  *(float4*)(O + i) = rr;
}

// ---------- launch ----------
extern "C" void kernel_launch(void* const* d_in, const int* in_sizes, int n_in,
                              void* d_out, int out_size, void* d_ws, size_t ws_size,
                              hipStream_t stream) {
  const float* X = (const float*)d_in[0];
  const float* Wq = (const float*)d_in[1];
  const float* Wk = (const float*)d_in[2];
  const float* Wv = (const float*)d_in[3];

  const size_t MB = 1024 * 1024;
  char* w = (char*)d_ws;
  u16* Xh = (u16*)(w + 0 * MB);    // 8 MB
  u16* Xl = (u16*)(w + 8 * MB);    // 8 MB
  u16* WqhT = (u16*)(w + 16 * MB); // 2 MB each
  u16* WqlT = (u16*)(w + 18 * MB);
  u16* WkhT = (u16*)(w + 20 * MB);
  u16* WklT = (u16*)(w + 22 * MB);
  u16* WvhT = (u16*)(w + 24 * MB);
  u16* Qh = (u16*)(w + 26 * MB);   // 8 MB each
  u16* Ql = (u16*)(w + 34 * MB);
  u16* Kh = (u16*)(w + 42 * MB);
  u16* Kl = (u16*)(w + 50 * MB);
  u16* VT = (u16*)(w + 58 * MB);   // 8 MB
  float* S = (float*)(w + 66 * MB);    // 64 MB
  u16* P = (u16*)(w + 26 * MB);        // aliases Qh..Kl (dead after s_kernel)
  float* Opart = (float*)(w + 66 * MB);// aliases S (dead after softmax), 64 MB
  // total: 130 MB

  prep_kernel<<<dim3(32, 32, 4), dim3(32, 8), 0, stream>>>(
      X, Wq, Wk, Wv, Xh, Xl, WqhT, WqlT, WkhT, WklT, WvhT);
  qkv_kernel<<<dim3(DIM / 128, SEQ / 128, 3), 256, 0, stream>>>(
      Xh, Xl, WqhT, WqlT, WkhT, WklT, WvhT, Qh, Ql, Kh, Kl, VT);
  s_kernel<<<dim3(SEQ / 128, SEQ / 128), 256, 0, stream>>>(Qh, Ql, Kh, Kl, S);
  softmax_kernel<<<SEQ, 256, 0, stream>>>(S, P);
  o_kernel<<<dim3(DIM / 128, SEQ / 128, 4), 256, 0, stream>>>(P, VT, Opart);
  o_reduce_kernel<<<(SEQ * DIM) / (256 * 4), 256, 0, stream>>>(Opart, (float*)d_out);
}